// Round 5
// baseline (361.186 us; speedup 1.0000x reference)
//
#include <hip/hip_runtime.h>
#include <math.h>

#define D_M 1024
#define S_L 8192
#define B_N 8
#define H_N 8
#define HD_ 128
#define HK_ 64
#define SCALE_ 0.08838834764831845f
#define NEG_INF_ -1e9f
#define RP32 1028          // row_lds32 pitch (floats): %32==4 -> 2-phase free; *4B %16==0
#define PTP 40             // p_lds pitch (halves): 80B rows, b128-clean

typedef _Float16 half8v __attribute__((ext_vector_type(8)));
typedef _Float16 half4v __attribute__((ext_vector_type(4)));
typedef float floatx4 __attribute__((ext_vector_type(4)));

// ---- q[kidx][i] = latent[kidx] . Wq[i] + bq[i]   (8x1024)
__global__ void k_q(const float* __restrict__ lat, const float* __restrict__ W,
                    const float* __restrict__ bias, float* __restrict__ q) {
  int g = blockIdx.x * blockDim.x + threadIdx.x;          // 8192
  int kidx = g >> 10, i = g & 1023;
  const float* wr = W + (size_t)i * D_M;
  const float* lr = lat + kidx * D_M;
  float acc = bias[i];
  #pragma unroll 4
  for (int t = 0; t < D_M; t += 4) {
    float4 w = *(const float4*)(wr + t);
    float4 l = *(const float4*)(lr + t);
    acc += w.x*l.x + w.y*l.y + w.z*l.z + w.w*l.w;
  }
  q[g] = acc;
}

// ---- qtr[(j>>3)][hk][j&7] = fp16( SCALE * sum_dd q[kidx][h*128+dd] * Wk[h*128+dd][j] )
//      (MFMA-B-fragment-friendly layout: 16 consecutive lanes read 256B contiguous)
__global__ void k_qt(const float* __restrict__ q, const float* __restrict__ W,
                     const float* __restrict__ bias, _Float16* __restrict__ qtr,
                     float* __restrict__ qconst) {
  int g = blockIdx.x * blockDim.x + threadIdx.x;          // 65536
  int hk = g >> 10, j = g & 1023;
  int h = hk >> 3, kidx = hk & 7;
  const float* qr = q + kidx * D_M + h * HD_;
  const float* wb = W + ((size_t)D_M + (size_t)h * HD_) * D_M + j;
  float acc = 0.f;
  #pragma unroll 4
  for (int dd = 0; dd < HD_; ++dd)
    acc += qr[dd] * wb[(size_t)dd * D_M];
  qtr[((j >> 3) * 64 + hk) * 8 + (j & 7)] = (_Float16)(acc * SCALE_);
  if (j == 0) {
    const float* bk = bias + D_M + h * HD_;
    float c = 0.f;
    for (int dd = 0; dd < HD_; ++dd) c += qr[dd] * bk[dd];
    qconst[hk] = c * SCALE_;
  }
}

// ---- fused: per (b, s-chunk of 256): QK^T -> online softmax -> PV
// grid 256 = b(8) x sc(32); block 512 (8 waves), 1 block/CU
// partial[b][sc][hk][1024] (pre-normalized, relative to chunk max), cm/cl = chunk (m,l)
__global__ __launch_bounds__(512, 2) void k_fused(
    const float* __restrict__ hsrc, const _Float16* __restrict__ qtr,
    const float* __restrict__ qc, const int* __restrict__ mask,
    float* __restrict__ partial, float* __restrict__ cm, float* __restrict__ cl) {
  __shared__ float row_lds32[32 * RP32];      // 131584 B: h tile [32 s][1024 d] fp32
  __shared__ float score_lds[32][66];         // 8448 B
  __shared__ __align__(16) _Float16 p_lds[64 * PTP];  // 5120 B
  __shared__ float stats_m[64], stats_l[64], fac_lds[64];
  __shared__ int mask_lds[32];
  const int tid = threadIdx.x;
  const int b  = blockIdx.x >> 5;
  const int sc = blockIdx.x & 31;
  const int w = tid >> 6, l = tid & 63;
  const int l15 = l & 15, kc = l >> 4;
  const int sh = w >> 2, hq = w & 3;          // QK: wave = s-half x hk-quad
  const int shk = tid >> 3, so = tid & 7;     // softmax: 8 threads per hk
  const float* hb = hsrc + ((size_t)b * S_L + sc * 256) * D_M;

  if (tid < 64) { stats_m[tid] = -3.4e38f; stats_l[tid] = 0.f; }
  const float qcv = qc[shk];
  floatx4 acc[4][8];                          // PV acc: [hk-frag][j-frag], 128 VGPR
  #pragma unroll
  for (int mf = 0; mf < 4; ++mf)
    #pragma unroll
    for (int nf = 0; nf < 8; ++nf) acc[mf][nf] = (floatx4){0.f, 0.f, 0.f, 0.f};

  for (int tt = 0; tt < 8; ++tt) {
    __syncthreads();                          // prev tile's PV done with row_lds
    // stage h tile [32][1024] fp32 -> LDS, fully coalesced (4KB contiguous per row)
    #pragma unroll
    for (int q2 = 0; q2 < 16; ++q2) {
      int idx = tid + q2 * 512;               // float4 id 0..8191
      int rr = idx >> 8, cc = idx & 255;
      float4 v = *(const float4*)(hb + (size_t)(tt * 32 + rr) * D_M + cc * 4);
      *(floatx4*)(row_lds32 + rr * RP32 + cc * 4) = (floatx4){v.x, v.y, v.z, v.w};
    }
    if (tid < 32) mask_lds[tid] = mask[b * S_L + sc * 256 + tt * 32 + tid];
    __syncthreads();                          // tile ready
    // ---- QK^T: C[16s x 16hk] per wave, full-d contraction (32 ksteps)
    {
      floatx4 sacc = (floatx4){0.f, 0.f, 0.f, 0.f};
      const float* ar = row_lds32 + (size_t)(sh * 16 + l15) * RP32 + kc * 8;
      const _Float16* br = qtr + (size_t)(hq * 16 + l15) * 8 + kc * 512;
      #pragma unroll
      for (int kk = 0; kk < 32; ++kk) {
        floatx4 a0 = *(const floatx4*)(ar + kk * 32);
        floatx4 a1 = *(const floatx4*)(ar + kk * 32 + 4);
        half8v af;
        af[0] = (_Float16)a0[0]; af[1] = (_Float16)a0[1];
        af[2] = (_Float16)a0[2]; af[3] = (_Float16)a0[3];
        af[4] = (_Float16)a1[0]; af[5] = (_Float16)a1[1];
        af[6] = (_Float16)a1[2]; af[7] = (_Float16)a1[3];
        half8v bf = *(const half8v*)(br + (size_t)kk * 2048);
        sacc = __builtin_amdgcn_mfma_f32_16x16x32_f16(af, bf, sacc, 0, 0, 0);
      }
      #pragma unroll
      for (int r = 0; r < 4; ++r)
        score_lds[sh * 16 + kc * 4 + r][hq * 16 + l15] = sacc[r];
    }
    __syncthreads();                          // scores ready
    // ---- tile softmax + online update (thread = (hk, s-oct of 4))
    {
      float vv[4], mx = -3.4e38f;
      #pragma unroll
      for (int r = 0; r < 4; ++r) {
        float v = mask_lds[so * 4 + r] ? (score_lds[so * 4 + r][shk] + qcv) : NEG_INF_;
        vv[r] = v; mx = fmaxf(mx, v);
      }
      #pragma unroll
      for (int o = 1; o < 8; o <<= 1) mx = fmaxf(mx, __shfl_xor(mx, o, 64));
      float mold = stats_m[shk];
      float mnew = fmaxf(mold, mx);
      float ps = 0.f; half4v pv;
      #pragma unroll
      for (int r = 0; r < 4; ++r) {
        float e = __expf(vv[r] - mnew);
        ps += e; pv[r] = (_Float16)e;
      }
      *(half4v*)(p_lds + shk * PTP + so * 4) = pv;
      #pragma unroll
      for (int o = 1; o < 8; o <<= 1) ps += __shfl_xor(ps, o, 64);
      if (so == 0) {
        float fac = __expf(mold - mnew);
        fac_lds[shk] = fac;
        stats_m[shk] = mnew;
        stats_l[shk] = stats_l[shk] * fac + ps;
      }
    }
    __syncthreads();                          // p/fac ready
    // ---- PV: rescale acc, then acc[hk][j] += p[hk][s32] . h[s32][j]
    {
      float facr[4][4];
      #pragma unroll
      for (int mf = 0; mf < 4; ++mf)
        #pragma unroll
        for (int r = 0; r < 4; ++r) facr[mf][r] = fac_lds[mf * 16 + kc * 4 + r];
      #pragma unroll
      for (int mf = 0; mf < 4; ++mf)
        #pragma unroll
        for (int nf = 0; nf < 8; ++nf)
          #pragma unroll
          for (int r = 0; r < 4; ++r) acc[mf][nf][r] *= facr[mf][r];
      half8v ap[4];
      #pragma unroll
      for (int mf = 0; mf < 4; ++mf)
        ap[mf] = *(const half8v*)(p_lds + (mf * 16 + l15) * PTP + kc * 8);
      #pragma unroll
      for (int nf = 0; nf < 8; ++nf) {
        const int j = w * 128 + nf * 16 + l15;
        half8v bv;
        #pragma unroll
        for (int e = 0; e < 8; ++e)
          bv[e] = (_Float16)row_lds32[(size_t)(kc * 8 + e) * RP32 + j];
        #pragma unroll
        for (int mf = 0; mf < 4; ++mf)
          acc[mf][nf] = __builtin_amdgcn_mfma_f32_16x16x32_f16(ap[mf], bv, acc[mf][nf], 0, 0, 0);
      }
    }
  }
  __syncthreads();
  // ---- epilogue: partial ctx + chunk stats
  float* pb = partial + ((size_t)(b * 32 + sc) * 64) * 1024;
  #pragma unroll
  for (int mf = 0; mf < 4; ++mf)
    #pragma unroll
    for (int r = 0; r < 4; ++r) {
      int hk = mf * 16 + kc * 4 + r;
      #pragma unroll
      for (int nf = 0; nf < 8; ++nf)
        pb[(size_t)hk * 1024 + w * 128 + nf * 16 + l15] = acc[mf][nf][r];
    }
  if (tid < 64) {
    cm[(size_t)(b * 32 + sc) * 64 + tid] = stats_m[tid];
    cl[(size_t)(b * 32 + sc) * 64 + tid] = stats_l[tid];
  }
}

// ---- global softmax stats across 32 chunks: wsc = exp(m_sc - M) / L_tot
__global__ void k_fstats(const float* __restrict__ cm, const float* __restrict__ cl,
                         float* __restrict__ wsc) {
  int t = blockIdx.x * blockDim.x + threadIdx.x;   // 512 = b*64 + hk
  int b = t >> 6, hk = t & 63;
  float M = -3.4e38f;
  for (int s = 0; s < 32; ++s) M = fmaxf(M, cm[b * 2048 + s * 64 + hk]);
  float L = 0.f;
  for (int s = 0; s < 32; ++s)
    L += cl[b * 2048 + s * 64 + hk] * __expf(cm[b * 2048 + s * 64 + hk] - M);
  float inv = 1.f / L;
  for (int s = 0; s < 32; ++s)
    wsc[b * 2048 + s * 64 + hk] = __expf(cm[b * 2048 + s * 64 + hk] - M) * inv;
}

// ---- ctxh[b][hk][j] = sum_sc partial * wsc
__global__ void k_comb(const float* __restrict__ partial, const float* __restrict__ wsc,
                       float* __restrict__ ctxh) {
  int g = blockIdx.x * blockDim.x + threadIdx.x;   // 131072 float4s
  int b = g >> 14, rem = g & 16383;
  int hk = rem >> 8, j4 = rem & 255;
  const float* pb = partial + ((size_t)b * 2048 + hk) * 1024 + j4 * 4;
  float4 s = make_float4(0.f, 0.f, 0.f, 0.f);
  for (int sc_ = 0; sc_ < 32; ++sc_) {
    float wv = wsc[b * 2048 + sc_ * 64 + hk];
    float4 v = *(const float4*)(pb + (size_t)sc_ * 65536);
    s.x += wv * v.x; s.y += wv * v.y; s.z += wv * v.z; s.w += wv * v.w;
  }
  *(float4*)(ctxh + ((size_t)b * HK_ + hk) * D_M + j4 * 4) = s;
}

// ---- ctx[b][kidx][i] = Wv[i].ctxh[b][hk(i,kidx)] + bv[i]
__global__ void k_ctx(const float* __restrict__ ctxh, const float* __restrict__ W,
                      const float* __restrict__ bias, float* __restrict__ ctx) {
  int g = blockIdx.x * blockDim.x + threadIdx.x;   // 65536
  int b = g >> 13, kidx = (g >> 10) & 7, i = g & 1023;
  int hk = (i >> 7) * 8 + kidx;
  const float* wr = W + ((size_t)2 * D_M + i) * D_M;
  const float* xr = ctxh + ((size_t)b * HK_ + hk) * D_M;
  float acc = bias[2 * D_M + i];
  #pragma unroll 4
  for (int t = 0; t < D_M; t += 4) {
    float4 w = *(const float4*)(wr + t);
    float4 x = *(const float4*)(xr + t);
    acc += w.x*x.x + w.y*x.y + w.z*x.z + w.w*x.w;
  }
  ctx[g] = acc;
}

// ---- pooled[b][kidx][i] = Wout[i].ctx[b][kidx] + bo[i]
__global__ void k_pool(const float* __restrict__ ctx, const float* __restrict__ W,
                       const float* __restrict__ bias, float* __restrict__ pooled) {
  int g = blockIdx.x * blockDim.x + threadIdx.x;   // 65536
  int b = g >> 13, kidx = (g >> 10) & 7, i = g & 1023;
  const float* wr = W + (size_t)i * D_M;
  const float* xr = ctx + ((size_t)b * 8 + kidx) * D_M;
  float acc = bias[i];
  #pragma unroll 4
  for (int t = 0; t < D_M; t += 4) {
    float4 w = *(const float4*)(wr + t);
    float4 x = *(const float4*)(xr + t);
    acc += w.x*x.x + w.y*x.y + w.z*x.z + w.w*x.w;
  }
  pooled[g] = acc;
}

// ---- LayerNorm per (b,kidx) then mean over kidx -> out[b][i]
__global__ void k_ln(const float* __restrict__ pooled, const float* __restrict__ gamma,
                     const float* __restrict__ beta, float* __restrict__ out) {
  __shared__ float red[256];
  int b = blockIdx.x, tid = threadIdx.x;
  float acc[4] = {0.f, 0.f, 0.f, 0.f};
  for (int kidx = 0; kidx < 8; ++kidx) {
    const float* row = pooled + ((size_t)b * 8 + kidx) * D_M;
    float v[4]; float s = 0.f;
    #pragma unroll
    for (int c = 0; c < 4; ++c) { v[c] = row[tid + 256 * c]; s += v[c]; }
    red[tid] = s; __syncthreads();
    for (int off = 128; off > 0; off >>= 1) {
      if (tid < off) red[tid] += red[tid + off];
      __syncthreads();
    }
    float mu = red[0] * (1.f / 1024.f);
    __syncthreads();
    float ss = 0.f;
    #pragma unroll
    for (int c = 0; c < 4; ++c) { float dd = v[c] - mu; ss += dd * dd; }
    red[tid] = ss; __syncthreads();
    for (int off = 128; off > 0; off >>= 1) {
      if (tid < off) red[tid] += red[tid + off];
      __syncthreads();
    }
    float rstd = rsqrtf(red[0] * (1.f / 1024.f) + 1e-5f);
    __syncthreads();
    #pragma unroll
    for (int c = 0; c < 4; ++c) {
      int i = tid + 256 * c;
      acc[c] += ((v[c] - mu) * rstd * gamma[i] + beta[i]) * 0.125f;
    }
  }
  #pragma unroll
  for (int c = 0; c < 4; ++c) out[(size_t)b * D_M + tid + 256 * c] = acc[c];
}

extern "C" void kernel_launch(void* const* d_in, const int* in_sizes, int n_in,
                              void* d_out, int out_size, void* d_ws, size_t ws_size,
                              hipStream_t stream) {
  const float* hidden = (const float*)d_in[0];
  const float* latent = (const float*)d_in[1];
  const float* w_in   = (const float*)d_in[2];
  const float* b_in   = (const float*)d_in[3];
  const float* w_out  = (const float*)d_in[4];
  const float* b_out  = (const float*)d_in[5];
  const float* gamma  = (const float*)d_in[6];
  const float* beta   = (const float*)d_in[7];
  const int*   mask   = (const int*)d_in[8];
  float* out = (float*)d_out;
  float* ws = (float*)d_ws;
  // workspace (floats), ~70 MB total
  float* q       = ws;                        // 8192
  float* qc      = q + 8192;                  // 64
  float* cm      = qc + 64;                   // 16384 = [8][32][64]
  float* cl      = cm + 16384;                // 16384
  float* wsc     = cl + 16384;                // 16384
  _Float16* qtr  = (_Float16*)(wsc + 16384);  // 65536 halves (32768 slots)
  float* partial = wsc + 16384 + 32768;       // 16777216 = [8][32][64][1024]
  float* ctxh    = partial + 16777216;        // 524288
  float* ctx     = ctxh + 524288;             // 65536
  float* pooled  = ctx + 65536;               // 65536

  k_q     <<<32,  256, 0, stream>>>(latent, w_in, b_in, q);
  k_qt    <<<256, 256, 0, stream>>>(q, w_in, b_in, qtr, qc);
  k_fused <<<256, 512, 0, stream>>>(hidden, qtr, qc, mask, partial, cm, cl);
  k_fstats<<<2,   256, 0, stream>>>(cm, cl, wsc);
  k_comb  <<<512, 256, 0, stream>>>(partial, wsc, ctxh);
  k_ctx   <<<256, 256, 0, stream>>>(ctxh, w_in, b_in, ctx);
  k_pool  <<<256, 256, 0, stream>>>(ctx, w_out, b_out, pooled);
  k_ln    <<<8,   256, 0, stream>>>(pooled, gamma, beta, out);
}